// Round 18
// baseline (284.352 us; speedup 1.0000x reference)
//
#include <hip/hip_runtime.h>
#include <math.h>

#define NN 50000
#define EE 800000
// D=128, H=4, C=32, ED=64

typedef __bf16 bf16x8 __attribute__((ext_vector_type(8)));
typedef float f32x4 __attribute__((ext_vector_type(4)));
typedef float f32x2 __attribute__((ext_vector_type(2)));
typedef unsigned short ushort_t;
typedef unsigned int uint_t;

__device__ inline ushort_t f2bf(float f) {
  uint_t u = __float_as_uint(f);
  uint_t r = (u + 0x7fffu + ((u >> 16) & 1u)) >> 16;
  return (ushort_t)r;
}
__device__ inline float bflo(uint_t u) { return __uint_as_float(u << 16); }
__device__ inline float bfhi(uint_t u) { return __uint_as_float(u & 0xffff0000u); }

// fp8 e4m3: encode 4 floats -> one u32 using ONLY op_sel=false (low-word) ops
__device__ inline uint_t pk4_fp8(float a0, float a1, float a2, float a3) {
  a0 = fminf(fmaxf(a0, -448.f), 448.f);
  a1 = fminf(fmaxf(a1, -448.f), 448.f);
  a2 = fminf(fmaxf(a2, -448.f), 448.f);
  a3 = fminf(fmaxf(a3, -448.f), 448.f);
  uint_t lo = (uint_t)__builtin_amdgcn_cvt_pk_fp8_f32(a0, a1, 0, false) & 0xFFFFu;
  uint_t hi = (uint_t)__builtin_amdgcn_cvt_pk_fp8_f32(a2, a3, 0, false) & 0xFFFFu;
  return lo | (hi << 16);
}

__device__ inline void wave_sync() {
  asm volatile("s_waitcnt lgkmcnt(0)" ::: "memory");
  __builtin_amdgcn_wave_barrier();
}

// ---------------- prepA: wcomb + zero counts --------------------------------
__global__ __launch_bounds__(256) void k_prepA(const float* __restrict__ Wbeta,
                                               float* __restrict__ wcomb,
                                               int* __restrict__ counts) {
  int b = blockIdx.x;
  int o = threadIdx.x;
  if (b == 0) {
    if (o < 128) {
      wcomb[o]       = Wbeta[o]       + Wbeta[256 + o];   // w_out
      wcomb[128 + o] = Wbeta[128 + o] - Wbeta[256 + o];   // w_xr
    }
  } else {
    int i = (b - 1) * 256 + o;
    if (i < NN) counts[i] = 0;
  }
}

// ---------------- prepB: Wbt bf16 + bcat + WebT bf16 + hist-with-RANK -------
__global__ __launch_bounds__(256) void k_prepB(
    const float* __restrict__ Wq, const float* __restrict__ Wk,
    const float* __restrict__ Wv, const float* __restrict__ Ws,
    const float* __restrict__ bq, const float* __restrict__ bk,
    const float* __restrict__ bv, const float* __restrict__ bs,
    ushort_t* __restrict__ Wbt, float* __restrict__ bcat,
    const float* __restrict__ We, ushort_t* __restrict__ WebT,
    const int* __restrict__ ei, int* __restrict__ counts,
    int* __restrict__ rank) {
  int b = blockIdx.x;
  if (b >= 288) {
    int i = (b - 288) * 256 + threadIdx.x;
    if (i < EE) rank[i] = atomicAdd(&counts[ei[EE + i]], 1);
    return;
  }
  if (b >= 256) {
    int i = (b - 256) * 256 + threadIdx.x;   // 0..8191
    int c = i >> 6, k = i & 63;
    WebT[c * 64 + k] = f2bf(We[k * 128 + c]);  // [col][k]
    return;
  }
  int i = b * 256 + threadIdx.x;   // 0..65535
  int c = i >> 7, k = i & 127;
  float w;
  if (c < 128)      w = Wq[k * 128 + c];
  else if (c < 256) w = Wk[k * 128 + (c - 128)];
  else if (c < 384) w = Wv[k * 128 + (c - 256)];
  else              w = Ws[k * 128 + (c - 384)];
  Wbt[(size_t)c * 128 + k] = f2bf(w);
  if (i < 512) {
    float bb;
    if (i < 128)      bb = bq[i];
    else if (i < 256) bb = bk[i - 128];
    else if (i < 384) bb = bv[i - 256];
    else              bb = bs[i - 384];
    bcat[i] = bb;
  }
}

// ---------------- standalone single-block scan (1024 thr, int4) -------------
__global__ __launch_bounds__(1024) void k_scan(int* __restrict__ counts, int* __restrict__ offsets) {
  __shared__ int wsum[16];
  __shared__ int s_carry;
  int4* counts4 = (int4*)counts;
  int4* offsets4 = (int4*)offsets;
  int t = threadIdx.x, lane = t & 63, w = t >> 6;
  if (t == 0) s_carry = 0;
  __syncthreads();
  for (int base = 0; base < 12500; base += 1024) {
    int idx = base + t;
    int4 v = (idx < 12500) ? counts4[idx] : make_int4(0, 0, 0, 0);
    int e1 = v.x, e2 = e1 + v.y, e3 = e2 + v.z, tot = e3 + v.w;
    int s = tot;
#pragma unroll
    for (int off = 1; off < 64; off <<= 1) {
      int u = __shfl_up(s, off);
      if (lane >= off) s += u;
    }
    if (lane == 63) wsum[w] = s;
    __syncthreads();
    if (t == 0) {
      int ex = s_carry;
#pragma unroll
      for (int i = 0; i < 16; ++i) { int tv = wsum[i]; wsum[i] = ex; ex += tv; }
      s_carry = ex;
    }
    __syncthreads();
    int excl = wsum[w] + s - tot;
    if (idx < 12500) offsets4[idx] = make_int4(excl, excl + e1, excl + e2, excl + e3);
    __syncthreads();
  }
  if (t == 0) offsets[NN] = s_carry;
}

// ---------------- FUSED: fillw (blocks [0,6250)) + mm 64x64 (rest) ----------
// fillw: R17-proven reg-staged transposed eW GEMM -> fp8 CSR rows.
// mm: [N,128]@[128,512]+bias, 64x64 tiles so the LDS union stays 32KB and
// the memory-bound fillw blocks overlap the MFMA-bound mm blocks in one
// dispatch (HIP streams serialize kernels; fusion is the only overlap).
#define NBFILL 6250
__global__ __launch_bounds__(256) void k_mmfill(
    const int* __restrict__ ei, const int* __restrict__ offsets,
    const int* __restrict__ rank, const float* __restrict__ ea,
    const ushort_t* __restrict__ WebT, int* __restrict__ srcs,
    unsigned char* __restrict__ eaWperm,
    const float* __restrict__ x, const ushort_t* __restrict__ Wbt,
    const float* __restrict__ bcat, ushort_t* __restrict__ qb,
    ushort_t* __restrict__ kb, ushort_t* __restrict__ vb,
    ushort_t* __restrict__ xrb) {
  __shared__ union {
    struct { ushort_t As[64 * 128]; ushort_t Bs[64 * 128]; } mm;      // 32KB
    struct { ushort_t Bs[128 * 64]; uint_t sOut[64 * 32]; int sP[128]; } fw; // 24.6KB
  } U;
  int t = threadIdx.x, lane = t & 63, wv = t >> 6;
  int l15 = lane & 15, l4 = lane >> 4;

  if (blockIdx.x < NBFILL) {
    // ================= fillw =================
    int eb = blockIdx.x * 128;         // 6250*128 == EE

    float4 ld[2][2][2];
#pragma unroll
    for (int T = 0; T < 2; ++T)
#pragma unroll
      for (int ks = 0; ks < 2; ++ks) {
        const float4* p4 = (const float4*)(ea + (size_t)(eb + T * 64 + wv * 16 + l15) * 64
                                           + ks * 32 + l4 * 8);
        ld[T][ks][0] = p4[0];
        ld[T][ks][1] = p4[1];
      }

    if (t < 128) {
      int e = eb + t;
      int d = ei[EE + e];
      int p = offsets[d] + rank[e];
      U.fw.sP[t] = p;
      srcs[p] = ei[e];
    }
    for (int q = t; q < 1024; q += 256) {
      int c = q >> 3, j = q & 7;
      uint4 w = *(const uint4*)&WebT[(size_t)c * 64 + j * 8];
      *(uint4*)&U.fw.Bs[c * 64 + ((j * 8) ^ ((c & 7) << 3))] = w;
    }
    __syncthreads();

#pragma unroll
    for (int T = 0; T < 2; ++T) {
      bf16x8 bfr[2];
#pragma unroll
      for (int ks = 0; ks < 2; ++ks) {
        float4 f0 = ld[T][ks][0], f1 = ld[T][ks][1];
        union { uint4 u; bf16x8 v; } ub;
        ub.u.x = (uint_t)f2bf(f0.x) | ((uint_t)f2bf(f0.y) << 16);
        ub.u.y = (uint_t)f2bf(f0.z) | ((uint_t)f2bf(f0.w) << 16);
        ub.u.z = (uint_t)f2bf(f1.x) | ((uint_t)f2bf(f1.y) << 16);
        ub.u.w = (uint_t)f2bf(f1.z) | ((uint_t)f2bf(f1.w) << 16);
        bfr[ks] = ub.v;
      }

      f32x4 acc[8];
#pragma unroll
      for (int i = 0; i < 8; ++i) acc[i] = (f32x4){0.f, 0.f, 0.f, 0.f};
#pragma unroll
      for (int ks = 0; ks < 2; ++ks) {
        int kbv = ks * 32 + l4 * 8;
#pragma unroll
        for (int i = 0; i < 8; ++i) {
          int c = i * 16 + l15;
          bf16x8 af = *(const bf16x8*)&U.fw.Bs[c * 64 + (kbv ^ ((c & 7) << 3))];
          acc[i] = __builtin_amdgcn_mfma_f32_16x16x32_bf16(af, bfr[ks], acc[i], 0, 0, 0);
        }
      }

      wave_sync();
      uint_t* dst32 = &U.fw.sOut[wv * 512];
#pragma unroll
      for (int i = 0; i < 8; ++i)
        dst32[l15 * 32 + ((i * 4 + l4) ^ ((l15 & 7) << 2))] =
            pk4_fp8(acc[i][0], acc[i][1], acc[i][2], acc[i][3]);
      wave_sync();

      int elr = lane >> 2, seg = lane & 3;
      int sw = (elr & 7) << 2;
      const uint_t* src32 = &U.fw.sOut[wv * 512 + elr * 32];
      int w0 = (seg * 8) ^ sw;
      int w1 = (seg * 8 + 4) ^ sw;
      uint4 lo = *(const uint4*)&src32[w0];
      uint4 hi = *(const uint4*)&src32[w1];
      int p = U.fw.sP[T * 64 + wv * 16 + elr];
      unsigned char* dst = eaWperm + (size_t)p * 128 + seg * 32;
      *(uint4*)dst = lo;
      *(uint4*)(dst + 16) = hi;
    }
    return;
  }

  // ================= mm, 64x64 tile =================
  int mb = blockIdx.x - NBFILL;        // 0..6255
  int rb = (mb >> 3) * 64;             // 782 row tiles
  int cb = (mb & 7) * 64;              // 8 col tiles over 512

  for (int q = t; q < 1024; q += 256) {
    int r = q >> 4, j = q & 15;
    int row = rb + r;
    float4 f0 = make_float4(0.f, 0.f, 0.f, 0.f), f1 = f0;
    if (row < NN) {
      const float4* xp = (const float4*)&x[(size_t)row * 128 + j * 8];
      f0 = xp[0]; f1 = xp[1];
    }
    uint_t u0 = (uint_t)f2bf(f0.x) | ((uint_t)f2bf(f0.y) << 16);
    uint_t u1 = (uint_t)f2bf(f0.z) | ((uint_t)f2bf(f0.w) << 16);
    uint_t u2 = (uint_t)f2bf(f1.x) | ((uint_t)f2bf(f1.y) << 16);
    uint_t u3 = (uint_t)f2bf(f1.z) | ((uint_t)f2bf(f1.w) << 16);
    int e = r * 128 + ((j * 8) ^ ((r & 7) << 3));
    *(uint4*)&U.mm.As[e] = make_uint4(u0, u1, u2, u3);
  }
  for (int q = t; q < 1024; q += 256) {
    int c = q >> 4, j = q & 15;
    uint4 w = *(const uint4*)&Wbt[(size_t)(cb + c) * 128 + j * 8];
    int e = c * 128 + ((j * 8) ^ ((c & 7) << 3));
    *(uint4*)&U.mm.Bs[e] = w;
  }
  __syncthreads();

  int wr = wv >> 1, wc = wv & 1;

  f32x4 acc[2][2];
#pragma unroll
  for (int i = 0; i < 2; ++i)
#pragma unroll
    for (int j = 0; j < 2; ++j) acc[i][j] = (f32x4){0.f, 0.f, 0.f, 0.f};

#pragma unroll
  for (int ks = 0; ks < 4; ++ks) {
    int kbv = ks * 32 + l4 * 8;
    bf16x8 af[2], bfr[2];
#pragma unroll
    for (int i = 0; i < 2; ++i) {
      int r = wr * 32 + i * 16 + l15;
      af[i] = *(const bf16x8*)&U.mm.As[r * 128 + (kbv ^ ((r & 7) << 3))];
    }
#pragma unroll
    for (int j = 0; j < 2; ++j) {
      int c = wc * 32 + j * 16 + l15;
      bfr[j] = *(const bf16x8*)&U.mm.Bs[c * 128 + (kbv ^ ((c & 7) << 3))];
    }
#pragma unroll
    for (int i = 0; i < 2; ++i)
#pragma unroll
      for (int j = 0; j < 2; ++j)
        acc[i][j] = __builtin_amdgcn_mfma_f32_16x16x32_bf16(af[i], bfr[j], acc[i][j], 0, 0, 0);
  }

#pragma unroll
  for (int j = 0; j < 2; ++j) {
    int colg = cb + wc * 32 + j * 16 + l15;      // 0..511
    float bv = bcat[colg];
    ushort_t* outp = (colg < 128) ? qb : (colg < 256) ? kb : (colg < 384) ? vb : xrb;
    int cc = colg & 127;
#pragma unroll
    for (int i = 0; i < 2; ++i) {
#pragma unroll
      for (int reg = 0; reg < 4; ++reg) {
        int grow = rb + wr * 32 + i * 16 + l4 * 4 + reg;
        if (grow < NN)
          outp[(size_t)grow * 128 + cc] = f2bf(acc[i][j][reg] + bv);
      }
    }
  }
}

// ---------------- fused attention, SOFTWARE-PIPELINED chunks ----------------
__global__ __launch_bounds__(256) void k_attn(
    const ushort_t* __restrict__ qb, const ushort_t* __restrict__ xrb,
    const ushort_t* __restrict__ kb, const ushort_t* __restrict__ vb,
    const unsigned char* __restrict__ eaWperm,
    const int* __restrict__ offsets, const int* __restrict__ srcs,
    const float* __restrict__ x, const float* __restrict__ wcomb,
    const float* __restrict__ gamma, const float* __restrict__ beta_ln,
    float* __restrict__ out) {
  __shared__ float sQ[4][128];
  __shared__ unsigned char sEA[4][16][144];
  __shared__ float sA[4][64];
  __shared__ int   sS[4][16];

  int t = threadIdx.x, wv = t >> 6, l = t & 63;
  int n = blockIdx.x * 4 + wv;
  int h = l >> 4, m = l & 15;
  int c0 = 2 * l, c1 = c0 + 1;
  const float scale = 0.17677669529663687f;   // 1/sqrt(32)

  uint_t qw = *(const uint_t*)&qb[(size_t)n * 128 + c0];
  *(float2*)&sQ[wv][c0] = make_float2(bflo(qw) * scale, bfhi(qw) * scale);
  if (l < 16) sS[wv][l] = 0;

  int js = offsets[n], je = offsets[n + 1];
  float acc0 = 0.f, acc1 = 0.f, lsum = 0.f;

  uint4 e0 = {0,0,0,0}, e1 = {0,0,0,0};
  uint4 k0 = {0,0,0,0}, k1 = {0,0,0,0}, k2 = {0,0,0,0}, k3 = {0,0,0,0};
  int scur = 0;
  if (m < je - js) {
    scur = srcs[js + m];
    const uint4* erow = (const uint4*)(eaWperm + (size_t)(js + m) * 128 + 32 * h);
    e0 = erow[0]; e1 = erow[1];
    const uint4* krow = (const uint4*)(kb + (size_t)scur * 128 + 32 * h);
    k0 = krow[0]; k1 = krow[1]; k2 = krow[2]; k3 = krow[3];
  }

  for (int base = js; base < je; base += 16) {
    int nj = je - base; if (nj > 16) nj = 16;
    wave_sync();

    *(uint4*)&sEA[wv][m][32 * h]      = e0;
    *(uint4*)&sEA[wv][m][32 * h + 16] = e1;
    if (h == 0) sS[wv][m] = scur;

    uint4 ne0 = {0,0,0,0}, ne1 = {0,0,0,0};
    uint4 nk0 = {0,0,0,0}, nk1 = {0,0,0,0}, nk2 = {0,0,0,0}, nk3 = {0,0,0,0};
    int snx = 0;
    int nb = base + 16;
    if (nb < je && m < je - nb) {
      snx = srcs[nb + m];
      const uint4* erow = (const uint4*)(eaWperm + (size_t)(nb + m) * 128 + 32 * h);
      ne0 = erow[0]; ne1 = erow[1];
      const uint4* krow = (const uint4*)(kb + (size_t)snx * 128 + 32 * h);
      nk0 = krow[0]; nk1 = krow[1]; nk2 = krow[2]; nk3 = krow[3];
    }
    wave_sync();

    int4 s0 = *(const int4*)&sS[wv][0];
    int4 s1 = *(const int4*)&sS[wv][4];
    int4 s2 = *(const int4*)&sS[wv][8];
    int4 s3 = *(const int4*)&sS[wv][12];
    uint_t vva[8], vvb[8];
    {
      int sidx[8] = {s0.x, s0.y, s0.z, s0.w, s1.x, s1.y, s1.z, s1.w};
#pragma unroll
      for (int e = 0; e < 8; ++e)
        vva[e] = *(const uint_t*)(vb + (size_t)sidx[e] * 128 + c0);
    }
    {
      int sidx[8] = {s2.x, s2.y, s2.z, s2.w, s3.x, s3.y, s3.z, s3.w};
#pragma unroll
      for (int e = 0; e < 8; ++e)
        vvb[e] = *(const uint_t*)(vb + (size_t)sidx[e] * 128 + c0);
    }

    float z = 0.f;
    {
      const float* qp = &sQ[wv][32 * h];
      uint_t eu[8] = {e0.x, e0.y, e0.z, e0.w, e1.x, e1.y, e1.z, e1.w};
      uint_t ku[16] = {k0.x, k0.y, k0.z, k0.w, k1.x, k1.y, k1.z, k1.w,
                       k2.x, k2.y, k2.z, k2.w, k3.x, k3.y, k3.z, k3.w};
#pragma unroll
      for (int u = 0; u < 8; ++u) {
        f32x2 elo = __builtin_amdgcn_cvt_pk_f32_fp8(eu[u] & 0xFFFFu, false);
        f32x2 ehi = __builtin_amdgcn_cvt_pk_f32_fp8(eu[u] >> 16, false);
        float4 q4 = *(const float4*)&qp[4 * u];
        z += q4.x * (bflo(ku[2 * u]) + elo.x)
           + q4.y * (bfhi(ku[2 * u]) + elo.y)
           + q4.z * (bflo(ku[2 * u + 1]) + ehi.x)
           + q4.w * (bfhi(ku[2 * u + 1]) + ehi.y);
      }
    }
    float a = (m < nj) ? __expf(z) : 0.0f;
    lsum += a;
    sA[wv][l] = a;
    wave_sync();

    {
      f32x4 a0 = *(const f32x4*)&sA[wv][16 * h];
      f32x4 a1 = *(const f32x4*)&sA[wv][16 * h + 4];
#pragma unroll
      for (int e = 0; e < 8; ++e) {
        float ae = (e < 4) ? a0[e] : a1[e - 4];
        uint_t ew = (uint_t)*(const ushort_t*)&sEA[wv][e][2 * l];
        f32x2 ef = __builtin_amdgcn_cvt_pk_f32_fp8(ew, false);
        acc0 += ae * (bflo(vva[e]) + ef.x);
        acc1 += ae * (bfhi(vva[e]) + ef.y);
      }
    }
    if (nj > 8) {
      f32x4 a2 = *(const f32x4*)&sA[wv][16 * h + 8];
      f32x4 a3 = *(const f32x4*)&sA[wv][16 * h + 12];
#pragma unroll
      for (int e = 0; e < 8; ++e) {
        float ae = (e < 4) ? a2[e] : a3[e - 4];
        uint_t ew = (uint_t)*(const ushort_t*)&sEA[wv][8 + e][2 * l];
        f32x2 ef = __builtin_amdgcn_cvt_pk_f32_fp8(ew, false);
        acc0 += ae * (bflo(vvb[e]) + ef.x);
        acc1 += ae * (bfhi(vvb[e]) + ef.y);
      }
    }

    e0 = ne0; e1 = ne1; k0 = nk0; k1 = nk1; k2 = nk2; k3 = nk3; scur = snx;
  }

  lsum += __shfl_xor(lsum, 1); lsum += __shfl_xor(lsum, 2);
  lsum += __shfl_xor(lsum, 4); lsum += __shfl_xor(lsum, 8);

  float inv = (lsum > 0.f) ? (1.0f / lsum) : 1.0f;
  float o0 = acc0 * inv;
  float o1 = acc1 * inv;

  uint_t xw = *(const uint_t*)&xrb[(size_t)n * 128 + c0];
  float2 xrv = make_float2(bflo(xw), bfhi(xw));
  float bp = o0 * wcomb[c0] + o1 * wcomb[c1] + xrv.x * wcomb[128 + c0] + xrv.y * wcomb[128 + c1];
#pragma unroll
  for (int off = 32; off > 0; off >>= 1) bp += __shfl_xor(bp, off);
  float bgate = 1.0f / (1.0f + __expf(-bp));
  float r0 = bgate * xrv.x + (1.0f - bgate) * o0;
  float r1 = bgate * xrv.y + (1.0f - bgate) * o1;

  float2 xv = *(const float2*)&x[(size_t)n * 128 + c0];
  float ge0 = 0.5f * r0 * (1.0f + erff(r0 * 0.70710678118654752f)) + xv.x;
  float ge1 = 0.5f * r1 * (1.0f + erff(r1 * 0.70710678118654752f)) + xv.y;

  float s1 = ge0 + ge1;
  float s2 = ge0 * ge0 + ge1 * ge1;
#pragma unroll
  for (int off = 32; off > 0; off >>= 1) {
    s1 += __shfl_xor(s1, off);
    s2 += __shfl_xor(s2, off);
  }
  float mean = s1 * (1.0f / 128.0f);
  float var = s2 * (1.0f / 128.0f) - mean * mean;
  float rstd = rsqrtf(var + 1e-5f);
  float2 ov;
  ov.x = (ge0 - mean) * rstd * gamma[c0] + beta_ln[c0];
  ov.y = (ge1 - mean) * rstd * gamma[c1] + beta_ln[c1];
  *(float2*)&out[(size_t)n * 128 + c0] = ov;
}

// ---------------- launch ----------------
extern "C" void kernel_launch(void* const* d_in, const int* in_sizes, int n_in,
                              void* d_out, int out_size, void* d_ws, size_t ws_size,
                              hipStream_t stream) {
  const float* x   = (const float*)d_in[0];
  const int*   ei  = (const int*)d_in[1];
  const float* ea  = (const float*)d_in[2];
  const float* Wq  = (const float*)d_in[3];
  const float* bq  = (const float*)d_in[4];
  const float* Wk  = (const float*)d_in[5];
  const float* bk  = (const float*)d_in[6];
  const float* Wv  = (const float*)d_in[7];
  const float* bv  = (const float*)d_in[8];
  const float* We  = (const float*)d_in[9];
  const float* Wsk = (const float*)d_in[10];
  const float* bsk = (const float*)d_in[11];
  const float* Wb  = (const float*)d_in[12];
  const float* gamma = (const float*)d_in[13];
  const float* beta  = (const float*)d_in[14];
  float* out = (float*)d_out;

  char* cur = (char*)d_ws;
  auto alloc = [&](size_t bytes) {
    void* p = (void*)cur;
    cur += (bytes + 255) & ~(size_t)255;
    return p;
  };
  ushort_t*      qbuf    = (ushort_t*)alloc((size_t)NN * 128 * 2);
  ushort_t*      kbuf    = (ushort_t*)alloc((size_t)NN * 128 * 2);
  ushort_t*      vbuf    = (ushort_t*)alloc((size_t)NN * 128 * 2);
  ushort_t*      xrbuf   = (ushort_t*)alloc((size_t)NN * 128 * 2);
  unsigned char* eaWperm = (unsigned char*)alloc((size_t)EE * 128); // fp8 eW, CSR order
  int*           srcs    = (int*)alloc((size_t)EE * 4);
  int*           rank    = (int*)alloc((size_t)EE * 4);
  float*         wcomb   = (float*)alloc(256 * 4);
  float*         bcat    = (float*)alloc(512 * 4);
  ushort_t*      Wbt     = (ushort_t*)alloc((size_t)512 * 128 * 2);
  ushort_t*      WebT    = (ushort_t*)alloc((size_t)128 * 64 * 2);
  int*           counts  = (int*)alloc((size_t)NN * 4);
  int*           offsets = (int*)alloc((size_t)(NN + 4) * 4);

  k_prepA<<<197, 256, 0, stream>>>(Wb, wcomb, counts);
  k_prepB<<<288 + 3125, 256, 0, stream>>>(Wq, Wk, Wv, Wsk, bq, bk, bv, bsk,
                                          Wbt, bcat, We, WebT, ei, counts, rank);
  k_scan<<<1, 1024, 0, stream>>>(counts, offsets);
  k_mmfill<<<NBFILL + 6256, 256, 0, stream>>>(ei, offsets, rank, ea, WebT, srcs,
                                              eaWperm, x, Wbt, bcat, qbuf, kbuf,
                                              vbuf, xrbuf);
  k_attn<<<12500, 256, 0, stream>>>(qbuf, xrbuf, kbuf, vbuf, eaWperm, offsets,
                                    srcs, x, wcomb, gamma, beta, out);
}

// Round 19
// 278.441 us; speedup vs baseline: 1.0212x; 1.0212x over previous
//
#include <hip/hip_runtime.h>
#include <math.h>

#define NN 50000
#define EE 800000
// D=128, H=4, C=32, ED=64

typedef __bf16 bf16x8 __attribute__((ext_vector_type(8)));
typedef float f32x4 __attribute__((ext_vector_type(4)));
typedef float f32x2 __attribute__((ext_vector_type(2)));
typedef unsigned short ushort_t;
typedef unsigned int uint_t;

__device__ inline ushort_t f2bf(float f) {
  uint_t u = __float_as_uint(f);
  uint_t r = (u + 0x7fffu + ((u >> 16) & 1u)) >> 16;
  return (ushort_t)r;
}
__device__ inline float bflo(uint_t u) { return __uint_as_float(u << 16); }
__device__ inline float bfhi(uint_t u) { return __uint_as_float(u & 0xffff0000u); }

// fp8 e4m3: encode 4 floats -> one u32 using ONLY op_sel=false (low-word) ops
__device__ inline uint_t pk4_fp8(float a0, float a1, float a2, float a3) {
  a0 = fminf(fmaxf(a0, -448.f), 448.f);
  a1 = fminf(fmaxf(a1, -448.f), 448.f);
  a2 = fminf(fmaxf(a2, -448.f), 448.f);
  a3 = fminf(fmaxf(a3, -448.f), 448.f);
  uint_t lo = (uint_t)__builtin_amdgcn_cvt_pk_fp8_f32(a0, a1, 0, false) & 0xFFFFu;
  uint_t hi = (uint_t)__builtin_amdgcn_cvt_pk_fp8_f32(a2, a3, 0, false) & 0xFFFFu;
  return lo | (hi << 16);
}

__device__ inline void wave_sync() {
  asm volatile("s_waitcnt lgkmcnt(0)" ::: "memory");
  __builtin_amdgcn_wave_barrier();
}

// ---------------- prepA: wcomb + zero counts --------------------------------
__global__ __launch_bounds__(256) void k_prepA(const float* __restrict__ Wbeta,
                                               float* __restrict__ wcomb,
                                               int* __restrict__ counts) {
  int b = blockIdx.x;
  int o = threadIdx.x;
  if (b == 0) {
    if (o < 128) {
      wcomb[o]       = Wbeta[o]       + Wbeta[256 + o];   // w_out
      wcomb[128 + o] = Wbeta[128 + o] - Wbeta[256 + o];   // w_xr
    }
  } else {
    int i = (b - 1) * 256 + o;
    if (i < NN) counts[i] = 0;
  }
}

// ---------------- prepB: Wbt bf16 + bcat + WebT bf16 + hist-with-RANK -------
__global__ __launch_bounds__(256) void k_prepB(
    const float* __restrict__ Wq, const float* __restrict__ Wk,
    const float* __restrict__ Wv, const float* __restrict__ Ws,
    const float* __restrict__ bq, const float* __restrict__ bk,
    const float* __restrict__ bv, const float* __restrict__ bs,
    ushort_t* __restrict__ Wbt, float* __restrict__ bcat,
    const float* __restrict__ We, ushort_t* __restrict__ WebT,
    const int* __restrict__ ei, int* __restrict__ counts,
    int* __restrict__ rank) {
  int b = blockIdx.x;
  if (b >= 288) {
    int i = (b - 288) * 256 + threadIdx.x;
    if (i < EE) rank[i] = atomicAdd(&counts[ei[EE + i]], 1);
    return;
  }
  if (b >= 256) {
    int i = (b - 256) * 256 + threadIdx.x;   // 0..8191
    int c = i >> 6, k = i & 63;
    WebT[c * 64 + k] = f2bf(We[k * 128 + c]);  // [col][k]
    return;
  }
  int i = b * 256 + threadIdx.x;   // 0..65535
  int c = i >> 7, k = i & 127;
  float w;
  if (c < 128)      w = Wq[k * 128 + c];
  else if (c < 256) w = Wk[k * 128 + (c - 128)];
  else if (c < 384) w = Wv[k * 128 + (c - 256)];
  else              w = Ws[k * 128 + (c - 384)];
  Wbt[(size_t)c * 128 + k] = f2bf(w);
  if (i < 512) {
    float bb;
    if (i < 128)      bb = bq[i];
    else if (i < 256) bb = bk[i - 128];
    else if (i < 384) bb = bv[i - 256];
    else              bb = bs[i - 384];
    bcat[i] = bb;
  }
}

// ---------------- MFMA GEMM (+ scan block): [N,128] @ [128,512] + bias ------
__global__ __launch_bounds__(256) void k_mmscan(const float* __restrict__ x,
                                                const ushort_t* __restrict__ Wbt,
                                                const float* __restrict__ bcat,
                                                ushort_t* __restrict__ qb,
                                                ushort_t* __restrict__ kb,
                                                ushort_t* __restrict__ vb,
                                                ushort_t* __restrict__ xrb,
                                                int* __restrict__ counts,
                                                int* __restrict__ offsets) {
  __shared__ ushort_t As[128 * 128];
  __shared__ ushort_t Bs[128 * 128];
  int t = threadIdx.x;

  if (blockIdx.x == 391) {
    if (blockIdx.y != 0) return;
    __shared__ int wsum[4];
    __shared__ int s_carry;
    int4* counts4 = (int4*)counts;
    int4* offsets4 = (int4*)offsets;
    int lane = t & 63, w = t >> 6;
    if (t == 0) s_carry = 0;
    __syncthreads();
    for (int base = 0; base < 12500; base += 256) {
      int idx = base + t;
      int4 v = (idx < 12500) ? counts4[idx] : make_int4(0, 0, 0, 0);
      int e1 = v.x, e2 = e1 + v.y, e3 = e2 + v.z, tot = e3 + v.w;
      int s = tot;
#pragma unroll
      for (int off = 1; off < 64; off <<= 1) {
        int u = __shfl_up(s, off);
        if (lane >= off) s += u;
      }
      if (lane == 63) wsum[w] = s;
      __syncthreads();
      if (t == 0) {
        int ex = s_carry;
#pragma unroll
        for (int i = 0; i < 4; ++i) { int tv = wsum[i]; wsum[i] = ex; ex += tv; }
        s_carry = ex;
      }
      __syncthreads();
      int be = wsum[w] + s - tot;
      if (idx < 12500) offsets4[idx] = make_int4(be, be + e1, be + e2, be + e3);
      __syncthreads();
    }
    if (t == 0) offsets[NN] = s_carry;
    return;
  }

  int rb = blockIdx.x * 128;
  int cb = blockIdx.y * 128;

  for (int q = t; q < 2048; q += 256) {
    int r = q >> 4, j = q & 15;
    int row = rb + r;
    float4 f0 = make_float4(0.f, 0.f, 0.f, 0.f), f1 = f0;
    if (row < NN) {
      const float4* xp = (const float4*)&x[(size_t)row * 128 + j * 8];
      f0 = xp[0]; f1 = xp[1];
    }
    uint_t u0 = (uint_t)f2bf(f0.x) | ((uint_t)f2bf(f0.y) << 16);
    uint_t u1 = (uint_t)f2bf(f0.z) | ((uint_t)f2bf(f0.w) << 16);
    uint_t u2 = (uint_t)f2bf(f1.x) | ((uint_t)f2bf(f1.y) << 16);
    uint_t u3 = (uint_t)f2bf(f1.z) | ((uint_t)f2bf(f1.w) << 16);
    int e = r * 128 + ((j * 8) ^ ((r & 7) << 3));
    *(uint4*)&As[e] = make_uint4(u0, u1, u2, u3);
  }
  for (int q = t; q < 2048; q += 256) {
    int c = q >> 4, j = q & 15;
    uint4 w = *(const uint4*)&Wbt[(size_t)(cb + c) * 128 + j * 8];
    int e = c * 128 + ((j * 8) ^ ((c & 7) << 3));
    *(uint4*)&Bs[e] = w;
  }
  __syncthreads();

  int lane = t & 63;
  int wv = t >> 6;
  int wr = wv >> 1, wc = wv & 1;
  int l15 = lane & 15, l4 = lane >> 4;

  f32x4 acc[4][4];
#pragma unroll
  for (int i = 0; i < 4; ++i)
#pragma unroll
    for (int j = 0; j < 4; ++j) acc[i][j] = (f32x4){0.f, 0.f, 0.f, 0.f};

#pragma unroll
  for (int ks = 0; ks < 4; ++ks) {
    int kbv = ks * 32 + l4 * 8;
    bf16x8 af[4], bfr[4];
#pragma unroll
    for (int i = 0; i < 4; ++i) {
      int r = wr * 64 + i * 16 + l15;
      af[i] = *(const bf16x8*)&As[r * 128 + (kbv ^ ((r & 7) << 3))];
    }
#pragma unroll
    for (int j = 0; j < 4; ++j) {
      int c = wc * 64 + j * 16 + l15;
      bfr[j] = *(const bf16x8*)&Bs[c * 128 + (kbv ^ ((c & 7) << 3))];
    }
#pragma unroll
    for (int i = 0; i < 4; ++i)
#pragma unroll
      for (int j = 0; j < 4; ++j)
        acc[i][j] = __builtin_amdgcn_mfma_f32_16x16x32_bf16(af[i], bfr[j], acc[i][j], 0, 0, 0);
  }

  ushort_t* outp = (cb == 0) ? qb : (cb == 128) ? kb : (cb == 256) ? vb : xrb;
#pragma unroll
  for (int j = 0; j < 4; ++j) {
    int colg = wc * 64 + j * 16 + l15;
    float bv = bcat[cb + colg];
#pragma unroll
    for (int i = 0; i < 4; ++i) {
#pragma unroll
      for (int reg = 0; reg < 4; ++reg) {
        int grow = rb + wr * 64 + i * 16 + l4 * 4 + reg;
        if (grow < NN)
          outp[(size_t)grow * 128 + colg] = f2bf(acc[i][j][reg] + bv);
      }
    }
  }
}

// ---------------- fillw: 128 edges/block, reg-staged ea (R17-proven) --------
__global__ __launch_bounds__(256) void k_fillw(const int* __restrict__ ei,
                                               const int* __restrict__ offsets,
                                               const int* __restrict__ rank,
                                               const float* __restrict__ ea,
                                               const ushort_t* __restrict__ WebT,
                                               int* __restrict__ srcs,
                                               unsigned char* __restrict__ eaWperm) {
  __shared__ ushort_t Bs[128 * 64];    // WebT bf16 swizzled (16KB)
  __shared__ uint_t sOut[64 * 32];     // fp8 staging, per-wave 2KB (8KB)
  __shared__ int sP[128];
  int t = threadIdx.x, lane = t & 63, wv = t >> 6;
  int l15 = lane & 15, l4 = lane >> 4;
  int eb = blockIdx.x * 128;           // 6250*128 == EE

  float4 ld[2][2][2];
#pragma unroll
  for (int T = 0; T < 2; ++T)
#pragma unroll
    for (int ks = 0; ks < 2; ++ks) {
      const float4* p4 = (const float4*)(ea + (size_t)(eb + T * 64 + wv * 16 + l15) * 64
                                         + ks * 32 + l4 * 8);
      ld[T][ks][0] = p4[0];
      ld[T][ks][1] = p4[1];
    }

  if (t < 128) {
    int e = eb + t;
    int d = ei[EE + e];
    int p = offsets[d] + rank[e];
    sP[t] = p;
    srcs[p] = ei[e];
  }
  for (int q = t; q < 1024; q += 256) {
    int c = q >> 3, j = q & 7;
    uint4 w = *(const uint4*)&WebT[(size_t)c * 64 + j * 8];
    *(uint4*)&Bs[c * 64 + ((j * 8) ^ ((c & 7) << 3))] = w;
  }
  __syncthreads();

#pragma unroll
  for (int T = 0; T < 2; ++T) {
    bf16x8 bfr[2];
#pragma unroll
    for (int ks = 0; ks < 2; ++ks) {
      float4 f0 = ld[T][ks][0], f1 = ld[T][ks][1];
      union { uint4 u; bf16x8 v; } ub;
      ub.u.x = (uint_t)f2bf(f0.x) | ((uint_t)f2bf(f0.y) << 16);
      ub.u.y = (uint_t)f2bf(f0.z) | ((uint_t)f2bf(f0.w) << 16);
      ub.u.z = (uint_t)f2bf(f1.x) | ((uint_t)f2bf(f1.y) << 16);
      ub.u.w = (uint_t)f2bf(f1.z) | ((uint_t)f2bf(f1.w) << 16);
      bfr[ks] = ub.v;
    }

    f32x4 acc[8];
#pragma unroll
    for (int i = 0; i < 8; ++i) acc[i] = (f32x4){0.f, 0.f, 0.f, 0.f};
#pragma unroll
    for (int ks = 0; ks < 2; ++ks) {
      int kbv = ks * 32 + l4 * 8;
#pragma unroll
      for (int i = 0; i < 8; ++i) {
        int c = i * 16 + l15;
        bf16x8 af = *(const bf16x8*)&Bs[c * 64 + (kbv ^ ((c & 7) << 3))];
        acc[i] = __builtin_amdgcn_mfma_f32_16x16x32_bf16(af, bfr[ks], acc[i], 0, 0, 0);
      }
    }

    wave_sync();
    uint_t* dst32 = &sOut[wv * 512];
#pragma unroll
    for (int i = 0; i < 8; ++i)
      dst32[l15 * 32 + ((i * 4 + l4) ^ ((l15 & 7) << 2))] =
          pk4_fp8(acc[i][0], acc[i][1], acc[i][2], acc[i][3]);
    wave_sync();

    int elr = lane >> 2, seg = lane & 3;
    int sw = (elr & 7) << 2;
    const uint_t* src32 = &sOut[wv * 512 + elr * 32];
    int w0 = (seg * 8) ^ sw;
    int w1 = (seg * 8 + 4) ^ sw;
    uint4 lo = *(const uint4*)&src32[w0];
    uint4 hi = *(const uint4*)&src32[w1];
    int p = sP[T * 64 + wv * 16 + elr];
    unsigned char* dst = eaWperm + (size_t)p * 128 + seg * 32;
    *(uint4*)dst = lo;
    *(uint4*)(dst + 16) = hi;
  }
}

// ---------------- fused attention, pipelined + shfl-broadcast a -------------
// sA LDS round-trip replaced by intra-wave __shfl broadcasts (a for edge e of
// head h lives in lane 16h+e) -> one less wave_sync per chunk.
__global__ __launch_bounds__(256) void k_attn(
    const ushort_t* __restrict__ qb, const ushort_t* __restrict__ xrb,
    const ushort_t* __restrict__ kb, const ushort_t* __restrict__ vb,
    const unsigned char* __restrict__ eaWperm,
    const int* __restrict__ offsets, const int* __restrict__ srcs,
    const float* __restrict__ x, const float* __restrict__ wcomb,
    const float* __restrict__ gamma, const float* __restrict__ beta_ln,
    float* __restrict__ out) {
  __shared__ float sQ[4][128];
  __shared__ unsigned char sEA[4][16][144];
  __shared__ int   sS[4][16];

  int t = threadIdx.x, wv = t >> 6, l = t & 63;
  int n = blockIdx.x * 4 + wv;
  int h = l >> 4, m = l & 15;
  int c0 = 2 * l, c1 = c0 + 1;
  const float scale = 0.17677669529663687f;   // 1/sqrt(32)

  uint_t qw = *(const uint_t*)&qb[(size_t)n * 128 + c0];
  *(float2*)&sQ[wv][c0] = make_float2(bflo(qw) * scale, bfhi(qw) * scale);
  if (l < 16) sS[wv][l] = 0;

  int js = offsets[n], je = offsets[n + 1];
  float acc0 = 0.f, acc1 = 0.f, lsum = 0.f;

  uint4 e0 = {0,0,0,0}, e1 = {0,0,0,0};
  uint4 k0 = {0,0,0,0}, k1 = {0,0,0,0}, k2 = {0,0,0,0}, k3 = {0,0,0,0};
  int scur = 0;
  if (m < je - js) {
    scur = srcs[js + m];
    const uint4* erow = (const uint4*)(eaWperm + (size_t)(js + m) * 128 + 32 * h);
    e0 = erow[0]; e1 = erow[1];
    const uint4* krow = (const uint4*)(kb + (size_t)scur * 128 + 32 * h);
    k0 = krow[0]; k1 = krow[1]; k2 = krow[2]; k3 = krow[3];
  }

  for (int base = js; base < je; base += 16) {
    int nj = je - base; if (nj > 16) nj = 16;
    wave_sync();   // prior chunk's sEA/sS readers done

    *(uint4*)&sEA[wv][m][32 * h]      = e0;
    *(uint4*)&sEA[wv][m][32 * h + 16] = e1;
    if (h == 0) sS[wv][m] = scur;

    uint4 ne0 = {0,0,0,0}, ne1 = {0,0,0,0};
    uint4 nk0 = {0,0,0,0}, nk1 = {0,0,0,0}, nk2 = {0,0,0,0}, nk3 = {0,0,0,0};
    int snx = 0;
    int nb = base + 16;
    if (nb < je && m < je - nb) {
      snx = srcs[nb + m];
      const uint4* erow = (const uint4*)(eaWperm + (size_t)(nb + m) * 128 + 32 * h);
      ne0 = erow[0]; ne1 = erow[1];
      const uint4* krow = (const uint4*)(kb + (size_t)snx * 128 + 32 * h);
      nk0 = krow[0]; nk1 = krow[1]; nk2 = krow[2]; nk3 = krow[3];
    }
    wave_sync();   // sEA/sS visible

    int4 s0 = *(const int4*)&sS[wv][0];
    int4 s1 = *(const int4*)&sS[wv][4];
    int4 s2 = *(const int4*)&sS[wv][8];
    int4 s3 = *(const int4*)&sS[wv][12];
    uint_t vva[8], vvb[8];
    {
      int sidx[8] = {s0.x, s0.y, s0.z, s0.w, s1.x, s1.y, s1.z, s1.w};
#pragma unroll
      for (int e = 0; e < 8; ++e)
        vva[e] = *(const uint_t*)(vb + (size_t)sidx[e] * 128 + c0);
    }
    {
      int sidx[8] = {s2.x, s2.y, s2.z, s2.w, s3.x, s3.y, s3.z, s3.w};
#pragma unroll
      for (int e = 0; e < 8; ++e)
        vvb[e] = *(const uint_t*)(vb + (size_t)sidx[e] * 128 + c0);
    }

    float z = 0.f;
    {
      const float* qp = &sQ[wv][32 * h];
      uint_t eu[8] = {e0.x, e0.y, e0.z, e0.w, e1.x, e1.y, e1.z, e1.w};
      uint_t ku[16] = {k0.x, k0.y, k0.z, k0.w, k1.x, k1.y, k1.z, k1.w,
                       k2.x, k2.y, k2.z, k2.w, k3.x, k3.y, k3.z, k3.w};
#pragma unroll
      for (int u = 0; u < 8; ++u) {
        f32x2 elo = __builtin_amdgcn_cvt_pk_f32_fp8(eu[u] & 0xFFFFu, false);
        f32x2 ehi = __builtin_amdgcn_cvt_pk_f32_fp8(eu[u] >> 16, false);
        float4 q4 = *(const float4*)&qp[4 * u];
        z += q4.x * (bflo(ku[2 * u]) + elo.x)
           + q4.y * (bfhi(ku[2 * u]) + elo.y)
           + q4.z * (bflo(ku[2 * u + 1]) + ehi.x)
           + q4.w * (bfhi(ku[2 * u + 1]) + ehi.y);
      }
    }
    float a = (m < nj) ? __expf(z) : 0.0f;
    lsum += a;

    // phase B with shfl-broadcast a (lane 16h+e holds a of edge e, head h)
#pragma unroll
    for (int e = 0; e < 8; ++e) {
      float ae = __shfl(a, 16 * h + e);
      uint_t ew = (uint_t)*(const ushort_t*)&sEA[wv][e][2 * l];
      f32x2 ef = __builtin_amdgcn_cvt_pk_f32_fp8(ew, false);
      acc0 += ae * (bflo(vva[e]) + ef.x);
      acc1 += ae * (bfhi(vva[e]) + ef.y);
    }
    if (nj > 8) {
#pragma unroll
      for (int e = 0; e < 8; ++e) {
        float ae = __shfl(a, 16 * h + 8 + e);
        uint_t ew = (uint_t)*(const ushort_t*)&sEA[wv][8 + e][2 * l];
        f32x2 ef = __builtin_amdgcn_cvt_pk_f32_fp8(ew, false);
        acc0 += ae * (bflo(vvb[e]) + ef.x);
        acc1 += ae * (bfhi(vvb[e]) + ef.y);
      }
    }

    e0 = ne0; e1 = ne1; k0 = nk0; k1 = nk1; k2 = nk2; k3 = nk3; scur = snx;
  }

  lsum += __shfl_xor(lsum, 1); lsum += __shfl_xor(lsum, 2);
  lsum += __shfl_xor(lsum, 4); lsum += __shfl_xor(lsum, 8);

  float inv = (lsum > 0.f) ? (1.0f / lsum) : 1.0f;
  float o0 = acc0 * inv;
  float o1 = acc1 * inv;

  uint_t xw = *(const uint_t*)&xrb[(size_t)n * 128 + c0];
  float2 xrv = make_float2(bflo(xw), bfhi(xw));
  float bp = o0 * wcomb[c0] + o1 * wcomb[c1] + xrv.x * wcomb[128 + c0] + xrv.y * wcomb[128 + c1];
#pragma unroll
  for (int off = 32; off > 0; off >>= 1) bp += __shfl_xor(bp, off);
  float bgate = 1.0f / (1.0f + __expf(-bp));
  float r0 = bgate * xrv.x + (1.0f - bgate) * o0;
  float r1 = bgate * xrv.y + (1.0f - bgate) * o1;

  float2 xv = *(const float2*)&x[(size_t)n * 128 + c0];
  float ge0 = 0.5f * r0 * (1.0f + erff(r0 * 0.70710678118654752f)) + xv.x;
  float ge1 = 0.5f * r1 * (1.0f + erff(r1 * 0.70710678118654752f)) + xv.y;

  float s1 = ge0 + ge1;
  float s2 = ge0 * ge0 + ge1 * ge1;
#pragma unroll
  for (int off = 32; off > 0; off >>= 1) {
    s1 += __shfl_xor(s1, off);
    s2 += __shfl_xor(s2, off);
  }
  float mean = s1 * (1.0f / 128.0f);
  float var = s2 * (1.0f / 128.0f) - mean * mean;
  float rstd = rsqrtf(var + 1e-5f);
  float2 ov;
  ov.x = (ge0 - mean) * rstd * gamma[c0] + beta_ln[c0];
  ov.y = (ge1 - mean) * rstd * gamma[c1] + beta_ln[c1];
  *(float2*)&out[(size_t)n * 128 + c0] = ov;
}

// ---------------- launch ----------------
extern "C" void kernel_launch(void* const* d_in, const int* in_sizes, int n_in,
                              void* d_out, int out_size, void* d_ws, size_t ws_size,
                              hipStream_t stream) {
  const float* x   = (const float*)d_in[0];
  const int*   ei  = (const int*)d_in[1];
  const float* ea  = (const float*)d_in[2];
  const float* Wq  = (const float*)d_in[3];
  const float* bq  = (const float*)d_in[4];
  const float* Wk  = (const float*)d_in[5];
  const float* bk  = (const float*)d_in[6];
  const float* Wv  = (const float*)d_in[7];
  const float* bv  = (const float*)d_in[8];
  const float* We  = (const float*)d_in[9];
  const float* Wsk = (const float*)d_in[10];
  const float* bsk = (const float*)d_in[11];
  const float* Wb  = (const float*)d_in[12];
  const float* gamma = (const float*)d_in[13];
  const float* beta  = (const float*)d_in[14];
  float* out = (float*)d_out;

  char* cur = (char*)d_ws;
  auto alloc = [&](size_t bytes) {
    void* p = (void*)cur;
    cur += (bytes + 255) & ~(size_t)255;
    return p;
  };
  ushort_t*      qbuf    = (ushort_t*)alloc((size_t)NN * 128 * 2);
  ushort_t*      kbuf    = (ushort_t*)alloc((size_t)NN * 128 * 2);
  ushort_t*      vbuf    = (ushort_t*)alloc((size_t)NN * 128 * 2);
  ushort_t*      xrbuf   = (ushort_t*)alloc((size_t)NN * 128 * 2);
  unsigned char* eaWperm = (unsigned char*)alloc((size_t)EE * 128); // fp8 eW, CSR order
  int*           srcs    = (int*)alloc((size_t)EE * 4);
  int*           rank    = (int*)alloc((size_t)EE * 4);
  float*         wcomb   = (float*)alloc(256 * 4);
  float*         bcat    = (float*)alloc(512 * 4);
  ushort_t*      Wbt     = (ushort_t*)alloc((size_t)512 * 128 * 2);
  ushort_t*      WebT    = (ushort_t*)alloc((size_t)128 * 64 * 2);
  int*           counts  = (int*)alloc((size_t)NN * 4);
  int*           offsets = (int*)alloc((size_t)(NN + 4) * 4);

  k_prepA<<<197, 256, 0, stream>>>(Wb, wcomb, counts);
  k_prepB<<<288 + 3125, 256, 0, stream>>>(Wq, Wk, Wv, Wsk, bq, bk, bv, bsk,
                                          Wbt, bcat, We, WebT, ei, counts, rank);
  k_mmscan<<<dim3(392, 4), 256, 0, stream>>>(x, Wbt, bcat, qbuf, kbuf, vbuf,
                                             xrbuf, counts, offsets);
  k_fillw<<<6250, 256, 0, stream>>>(ei, offsets, rank, ea, WebT, srcs, eaWperm);
  k_attn<<<12500, 256, 0, stream>>>(qbuf, xrbuf, kbuf, vbuf, eaWperm, offsets,
                                    srcs, x, wcomb, gamma, beta, out);
}

// Round 20
// 275.640 us; speedup vs baseline: 1.0316x; 1.0102x over previous
//
#include <hip/hip_runtime.h>
#include <math.h>

#define NN 50000
#define EE 800000
// D=128, H=4, C=32, ED=64

typedef __bf16 bf16x8 __attribute__((ext_vector_type(8)));
typedef float f32x4 __attribute__((ext_vector_type(4)));
typedef float f32x2 __attribute__((ext_vector_type(2)));
typedef unsigned short ushort_t;
typedef unsigned int uint_t;

__device__ inline ushort_t f2bf(float f) {
  uint_t u = __float_as_uint(f);
  uint_t r = (u + 0x7fffu + ((u >> 16) & 1u)) >> 16;
  return (ushort_t)r;
}
__device__ inline float bflo(uint_t u) { return __uint_as_float(u << 16); }
__device__ inline float bfhi(uint_t u) { return __uint_as_float(u & 0xffff0000u); }

// fp8 e4m3: encode 4 floats -> one u32 using ONLY op_sel=false (low-word) ops
__device__ inline uint_t pk4_fp8(float a0, float a1, float a2, float a3) {
  a0 = fminf(fmaxf(a0, -448.f), 448.f);
  a1 = fminf(fmaxf(a1, -448.f), 448.f);
  a2 = fminf(fmaxf(a2, -448.f), 448.f);
  a3 = fminf(fmaxf(a3, -448.f), 448.f);
  uint_t lo = (uint_t)__builtin_amdgcn_cvt_pk_fp8_f32(a0, a1, 0, false) & 0xFFFFu;
  uint_t hi = (uint_t)__builtin_amdgcn_cvt_pk_fp8_f32(a2, a3, 0, false) & 0xFFFFu;
  return lo | (hi << 16);
}

__device__ inline void wave_sync() {
  asm volatile("s_waitcnt lgkmcnt(0)" ::: "memory");
  __builtin_amdgcn_wave_barrier();
}

// ---------------- prepB: Wbt bf16 + bcat + WebT bf16 + wcomb + hist/RANK ----
// b<256: Wbt+bcat ; b<288: WebT ; b==288: wcomb ; b>=289: hist (rank capture)
__global__ __launch_bounds__(256) void k_prepB(
    const float* __restrict__ Wq, const float* __restrict__ Wk,
    const float* __restrict__ Wv, const float* __restrict__ Ws,
    const float* __restrict__ bq, const float* __restrict__ bk,
    const float* __restrict__ bv, const float* __restrict__ bs,
    ushort_t* __restrict__ Wbt, float* __restrict__ bcat,
    const float* __restrict__ We, ushort_t* __restrict__ WebT,
    const float* __restrict__ Wbeta, float* __restrict__ wcomb,
    const int* __restrict__ ei, int* __restrict__ counts,
    int* __restrict__ rank) {
  int b = blockIdx.x;
  if (b >= 289) {
    int i = (b - 289) * 256 + threadIdx.x;
    if (i < EE) rank[i] = atomicAdd(&counts[ei[EE + i]], 1);
    return;
  }
  if (b == 288) {
    int o = threadIdx.x;
    if (o < 128) {
      wcomb[o]       = Wbeta[o]       + Wbeta[256 + o];   // w_out
      wcomb[128 + o] = Wbeta[128 + o] - Wbeta[256 + o];   // w_xr
    }
    return;
  }
  if (b >= 256) {
    int i = (b - 256) * 256 + threadIdx.x;   // 0..8191
    int c = i >> 6, k = i & 63;
    WebT[c * 64 + k] = f2bf(We[k * 128 + c]);  // [col][k]
    return;
  }
  int i = b * 256 + threadIdx.x;   // 0..65535
  int c = i >> 7, k = i & 127;
  float w;
  if (c < 128)      w = Wq[k * 128 + c];
  else if (c < 256) w = Wk[k * 128 + (c - 128)];
  else if (c < 384) w = Wv[k * 128 + (c - 256)];
  else              w = Ws[k * 128 + (c - 384)];
  Wbt[(size_t)c * 128 + k] = f2bf(w);
  if (i < 512) {
    float bb;
    if (i < 128)      bb = bq[i];
    else if (i < 256) bb = bk[i - 128];
    else if (i < 384) bb = bv[i - 256];
    else              bb = bs[i - 384];
    bcat[i] = bb;
  }
}

// ---------------- MFMA GEMM (+ scan block): [N,128] @ [128,512] + bias ------
__global__ __launch_bounds__(256) void k_mmscan(const float* __restrict__ x,
                                                const ushort_t* __restrict__ Wbt,
                                                const float* __restrict__ bcat,
                                                ushort_t* __restrict__ qb,
                                                ushort_t* __restrict__ kb,
                                                ushort_t* __restrict__ vb,
                                                ushort_t* __restrict__ xrb,
                                                int* __restrict__ counts,
                                                int* __restrict__ offsets) {
  __shared__ ushort_t As[128 * 128];
  __shared__ ushort_t Bs[128 * 128];
  int t = threadIdx.x;

  if (blockIdx.x == 391) {
    if (blockIdx.y != 0) return;
    __shared__ int wsum[4];
    __shared__ int s_carry;
    int4* counts4 = (int4*)counts;
    int4* offsets4 = (int4*)offsets;
    int lane = t & 63, w = t >> 6;
    if (t == 0) s_carry = 0;
    __syncthreads();
    for (int base = 0; base < 12500; base += 256) {
      int idx = base + t;
      int4 v = (idx < 12500) ? counts4[idx] : make_int4(0, 0, 0, 0);
      int e1 = v.x, e2 = e1 + v.y, e3 = e2 + v.z, tot = e3 + v.w;
      int s = tot;
#pragma unroll
      for (int off = 1; off < 64; off <<= 1) {
        int u = __shfl_up(s, off);
        if (lane >= off) s += u;
      }
      if (lane == 63) wsum[w] = s;
      __syncthreads();
      if (t == 0) {
        int ex = s_carry;
#pragma unroll
        for (int i = 0; i < 4; ++i) { int tv = wsum[i]; wsum[i] = ex; ex += tv; }
        s_carry = ex;
      }
      __syncthreads();
      int be = wsum[w] + s - tot;
      if (idx < 12500) offsets4[idx] = make_int4(be, be + e1, be + e2, be + e3);
      __syncthreads();
    }
    if (t == 0) offsets[NN] = s_carry;
    return;
  }

  int rb = blockIdx.x * 128;
  int cb = blockIdx.y * 128;

  for (int q = t; q < 2048; q += 256) {
    int r = q >> 4, j = q & 15;
    int row = rb + r;
    float4 f0 = make_float4(0.f, 0.f, 0.f, 0.f), f1 = f0;
    if (row < NN) {
      const float4* xp = (const float4*)&x[(size_t)row * 128 + j * 8];
      f0 = xp[0]; f1 = xp[1];
    }
    uint_t u0 = (uint_t)f2bf(f0.x) | ((uint_t)f2bf(f0.y) << 16);
    uint_t u1 = (uint_t)f2bf(f0.z) | ((uint_t)f2bf(f0.w) << 16);
    uint_t u2 = (uint_t)f2bf(f1.x) | ((uint_t)f2bf(f1.y) << 16);
    uint_t u3 = (uint_t)f2bf(f1.z) | ((uint_t)f2bf(f1.w) << 16);
    int e = r * 128 + ((j * 8) ^ ((r & 7) << 3));
    *(uint4*)&As[e] = make_uint4(u0, u1, u2, u3);
  }
  for (int q = t; q < 2048; q += 256) {
    int c = q >> 4, j = q & 15;
    uint4 w = *(const uint4*)&Wbt[(size_t)(cb + c) * 128 + j * 8];
    int e = c * 128 + ((j * 8) ^ ((c & 7) << 3));
    *(uint4*)&Bs[e] = w;
  }
  __syncthreads();

  int lane = t & 63;
  int wv = t >> 6;
  int wr = wv >> 1, wc = wv & 1;
  int l15 = lane & 15, l4 = lane >> 4;

  f32x4 acc[4][4];
#pragma unroll
  for (int i = 0; i < 4; ++i)
#pragma unroll
    for (int j = 0; j < 4; ++j) acc[i][j] = (f32x4){0.f, 0.f, 0.f, 0.f};

#pragma unroll
  for (int ks = 0; ks < 4; ++ks) {
    int kbv = ks * 32 + l4 * 8;
    bf16x8 af[4], bfr[4];
#pragma unroll
    for (int i = 0; i < 4; ++i) {
      int r = wr * 64 + i * 16 + l15;
      af[i] = *(const bf16x8*)&As[r * 128 + (kbv ^ ((r & 7) << 3))];
    }
#pragma unroll
    for (int j = 0; j < 4; ++j) {
      int c = wc * 64 + j * 16 + l15;
      bfr[j] = *(const bf16x8*)&Bs[c * 128 + (kbv ^ ((c & 7) << 3))];
    }
#pragma unroll
    for (int i = 0; i < 4; ++i)
#pragma unroll
      for (int j = 0; j < 4; ++j)
        acc[i][j] = __builtin_amdgcn_mfma_f32_16x16x32_bf16(af[i], bfr[j], acc[i][j], 0, 0, 0);
  }

  ushort_t* outp = (cb == 0) ? qb : (cb == 128) ? kb : (cb == 256) ? vb : xrb;
#pragma unroll
  for (int j = 0; j < 4; ++j) {
    int colg = wc * 64 + j * 16 + l15;
    float bv = bcat[cb + colg];
#pragma unroll
    for (int i = 0; i < 4; ++i) {
#pragma unroll
      for (int reg = 0; reg < 4; ++reg) {
        int grow = rb + wr * 64 + i * 16 + l4 * 4 + reg;
        if (grow < NN)
          outp[(size_t)grow * 128 + colg] = f2bf(acc[i][j][reg] + bv);
      }
    }
  }
}

// ---------------- fillw: 128 edges/block, reg-staged ea (R17-proven) --------
__global__ __launch_bounds__(256) void k_fillw(const int* __restrict__ ei,
                                               const int* __restrict__ offsets,
                                               const int* __restrict__ rank,
                                               const float* __restrict__ ea,
                                               const ushort_t* __restrict__ WebT,
                                               int* __restrict__ srcs,
                                               unsigned char* __restrict__ eaWperm) {
  __shared__ ushort_t Bs[128 * 64];    // WebT bf16 swizzled (16KB)
  __shared__ uint_t sOut[64 * 32];     // fp8 staging, per-wave 2KB (8KB)
  __shared__ int sP[128];
  int t = threadIdx.x, lane = t & 63, wv = t >> 6;
  int l15 = lane & 15, l4 = lane >> 4;
  int eb = blockIdx.x * 128;           // 6250*128 == EE

  float4 ld[2][2][2];
#pragma unroll
  for (int T = 0; T < 2; ++T)
#pragma unroll
    for (int ks = 0; ks < 2; ++ks) {
      const float4* p4 = (const float4*)(ea + (size_t)(eb + T * 64 + wv * 16 + l15) * 64
                                         + ks * 32 + l4 * 8);
      ld[T][ks][0] = p4[0];
      ld[T][ks][1] = p4[1];
    }

  if (t < 128) {
    int e = eb + t;
    int d = ei[EE + e];
    int p = offsets[d] + rank[e];
    sP[t] = p;
    srcs[p] = ei[e];
  }
  for (int q = t; q < 1024; q += 256) {
    int c = q >> 3, j = q & 7;
    uint4 w = *(const uint4*)&WebT[(size_t)c * 64 + j * 8];
    *(uint4*)&Bs[c * 64 + ((j * 8) ^ ((c & 7) << 3))] = w;
  }
  __syncthreads();

#pragma unroll
  for (int T = 0; T < 2; ++T) {
    bf16x8 bfr[2];
#pragma unroll
    for (int ks = 0; ks < 2; ++ks) {
      float4 f0 = ld[T][ks][0], f1 = ld[T][ks][1];
      union { uint4 u; bf16x8 v; } ub;
      ub.u.x = (uint_t)f2bf(f0.x) | ((uint_t)f2bf(f0.y) << 16);
      ub.u.y = (uint_t)f2bf(f0.z) | ((uint_t)f2bf(f0.w) << 16);
      ub.u.z = (uint_t)f2bf(f1.x) | ((uint_t)f2bf(f1.y) << 16);
      ub.u.w = (uint_t)f2bf(f1.z) | ((uint_t)f2bf(f1.w) << 16);
      bfr[ks] = ub.v;
    }

    f32x4 acc[8];
#pragma unroll
    for (int i = 0; i < 8; ++i) acc[i] = (f32x4){0.f, 0.f, 0.f, 0.f};
#pragma unroll
    for (int ks = 0; ks < 2; ++ks) {
      int kbv = ks * 32 + l4 * 8;
#pragma unroll
      for (int i = 0; i < 8; ++i) {
        int c = i * 16 + l15;
        bf16x8 af = *(const bf16x8*)&Bs[c * 64 + (kbv ^ ((c & 7) << 3))];
        acc[i] = __builtin_amdgcn_mfma_f32_16x16x32_bf16(af, bfr[ks], acc[i], 0, 0, 0);
      }
    }

    wave_sync();
    uint_t* dst32 = &sOut[wv * 512];
#pragma unroll
    for (int i = 0; i < 8; ++i)
      dst32[l15 * 32 + ((i * 4 + l4) ^ ((l15 & 7) << 2))] =
          pk4_fp8(acc[i][0], acc[i][1], acc[i][2], acc[i][3]);
    wave_sync();

    int elr = lane >> 2, seg = lane & 3;
    int sw = (elr & 7) << 2;
    const uint_t* src32 = &sOut[wv * 512 + elr * 32];
    int w0 = (seg * 8) ^ sw;
    int w1 = (seg * 8 + 4) ^ sw;
    uint4 lo = *(const uint4*)&src32[w0];
    uint4 hi = *(const uint4*)&src32[w1];
    int p = sP[T * 64 + wv * 16 + elr];
    unsigned char* dst = eaWperm + (size_t)p * 128 + seg * 32;
    *(uint4*)dst = lo;
    *(uint4*)(dst + 16) = hi;
  }
}

// ---------------- fused attention, pipelined + shfl-broadcast a -------------
__global__ __launch_bounds__(256) void k_attn(
    const ushort_t* __restrict__ qb, const ushort_t* __restrict__ xrb,
    const ushort_t* __restrict__ kb, const ushort_t* __restrict__ vb,
    const unsigned char* __restrict__ eaWperm,
    const int* __restrict__ offsets, const int* __restrict__ srcs,
    const float* __restrict__ x, const float* __restrict__ wcomb,
    const float* __restrict__ gamma, const float* __restrict__ beta_ln,
    float* __restrict__ out) {
  __shared__ float sQ[4][128];
  __shared__ unsigned char sEA[4][16][144];
  __shared__ int   sS[4][16];

  int t = threadIdx.x, wv = t >> 6, l = t & 63;
  int n = blockIdx.x * 4 + wv;
  int h = l >> 4, m = l & 15;
  int c0 = 2 * l, c1 = c0 + 1;
  const float scale = 0.17677669529663687f;   // 1/sqrt(32)

  uint_t qw = *(const uint_t*)&qb[(size_t)n * 128 + c0];
  *(float2*)&sQ[wv][c0] = make_float2(bflo(qw) * scale, bfhi(qw) * scale);
  if (l < 16) sS[wv][l] = 0;

  int js = offsets[n], je = offsets[n + 1];
  float acc0 = 0.f, acc1 = 0.f, lsum = 0.f;

  uint4 e0 = {0,0,0,0}, e1 = {0,0,0,0};
  uint4 k0 = {0,0,0,0}, k1 = {0,0,0,0}, k2 = {0,0,0,0}, k3 = {0,0,0,0};
  int scur = 0;
  if (m < je - js) {
    scur = srcs[js + m];
    const uint4* erow = (const uint4*)(eaWperm + (size_t)(js + m) * 128 + 32 * h);
    e0 = erow[0]; e1 = erow[1];
    const uint4* krow = (const uint4*)(kb + (size_t)scur * 128 + 32 * h);
    k0 = krow[0]; k1 = krow[1]; k2 = krow[2]; k3 = krow[3];
  }

  for (int base = js; base < je; base += 16) {
    int nj = je - base; if (nj > 16) nj = 16;
    wave_sync();   // prior chunk's sEA/sS readers done

    *(uint4*)&sEA[wv][m][32 * h]      = e0;
    *(uint4*)&sEA[wv][m][32 * h + 16] = e1;
    if (h == 0) sS[wv][m] = scur;

    uint4 ne0 = {0,0,0,0}, ne1 = {0,0,0,0};
    uint4 nk0 = {0,0,0,0}, nk1 = {0,0,0,0}, nk2 = {0,0,0,0}, nk3 = {0,0,0,0};
    int snx = 0;
    int nb = base + 16;
    if (nb < je && m < je - nb) {
      snx = srcs[nb + m];
      const uint4* erow = (const uint4*)(eaWperm + (size_t)(nb + m) * 128 + 32 * h);
      ne0 = erow[0]; ne1 = erow[1];
      const uint4* krow = (const uint4*)(kb + (size_t)snx * 128 + 32 * h);
      nk0 = krow[0]; nk1 = krow[1]; nk2 = krow[2]; nk3 = krow[3];
    }
    wave_sync();   // sEA/sS visible

    int4 s0 = *(const int4*)&sS[wv][0];
    int4 s1 = *(const int4*)&sS[wv][4];
    uint_t vva[8], vvb[8];
    {
      int sidx[8] = {s0.x, s0.y, s0.z, s0.w, s1.x, s1.y, s1.z, s1.w};
#pragma unroll
      for (int e = 0; e < 8; ++e)
        vva[e] = *(const uint_t*)(vb + (size_t)sidx[e] * 128 + c0);
    }
    if (nj > 8) {
      int4 s2 = *(const int4*)&sS[wv][8];
      int4 s3 = *(const int4*)&sS[wv][12];
      int sidx[8] = {s2.x, s2.y, s2.z, s2.w, s3.x, s3.y, s3.z, s3.w};
#pragma unroll
      for (int e = 0; e < 8; ++e)
        vvb[e] = *(const uint_t*)(vb + (size_t)sidx[e] * 128 + c0);
    }

    float z = 0.f;
    {
      const float* qp = &sQ[wv][32 * h];
      uint_t eu[8] = {e0.x, e0.y, e0.z, e0.w, e1.x, e1.y, e1.z, e1.w};
      uint_t ku[16] = {k0.x, k0.y, k0.z, k0.w, k1.x, k1.y, k1.z, k1.w,
                       k2.x, k2.y, k2.z, k2.w, k3.x, k3.y, k3.z, k3.w};
#pragma unroll
      for (int u = 0; u < 8; ++u) {
        f32x2 elo = __builtin_amdgcn_cvt_pk_f32_fp8(eu[u] & 0xFFFFu, false);
        f32x2 ehi = __builtin_amdgcn_cvt_pk_f32_fp8(eu[u] >> 16, false);
        float4 q4 = *(const float4*)&qp[4 * u];
        z += q4.x * (bflo(ku[2 * u]) + elo.x)
           + q4.y * (bfhi(ku[2 * u]) + elo.y)
           + q4.z * (bflo(ku[2 * u + 1]) + ehi.x)
           + q4.w * (bfhi(ku[2 * u + 1]) + ehi.y);
      }
    }
    float a = (m < nj) ? __expf(z) : 0.0f;
    lsum += a;

    // phase B with shfl-broadcast a (lane 16h+e holds a of edge e, head h)
#pragma unroll
    for (int e = 0; e < 8; ++e) {
      float ae = __shfl(a, 16 * h + e);
      uint_t ew = (uint_t)*(const ushort_t*)&sEA[wv][e][2 * l];
      f32x2 ef = __builtin_amdgcn_cvt_pk_f32_fp8(ew, false);
      acc0 += ae * (bflo(vva[e]) + ef.x);
      acc1 += ae * (bfhi(vva[e]) + ef.y);
    }
    if (nj > 8) {
#pragma unroll
      for (int e = 0; e < 8; ++e) {
        float ae = __shfl(a, 16 * h + 8 + e);
        uint_t ew = (uint_t)*(const ushort_t*)&sEA[wv][8 + e][2 * l];
        f32x2 ef = __builtin_amdgcn_cvt_pk_f32_fp8(ew, false);
        acc0 += ae * (bflo(vvb[e]) + ef.x);
        acc1 += ae * (bfhi(vvb[e]) + ef.y);
      }
    }

    e0 = ne0; e1 = ne1; k0 = nk0; k1 = nk1; k2 = nk2; k3 = nk3; scur = snx;
  }

  lsum += __shfl_xor(lsum, 1); lsum += __shfl_xor(lsum, 2);
  lsum += __shfl_xor(lsum, 4); lsum += __shfl_xor(lsum, 8);

  float inv = (lsum > 0.f) ? (1.0f / lsum) : 1.0f;
  float o0 = acc0 * inv;
  float o1 = acc1 * inv;

  uint_t xw = *(const uint_t*)&xrb[(size_t)n * 128 + c0];
  float2 xrv = make_float2(bflo(xw), bfhi(xw));
  float bp = o0 * wcomb[c0] + o1 * wcomb[c1] + xrv.x * wcomb[128 + c0] + xrv.y * wcomb[128 + c1];
#pragma unroll
  for (int off = 32; off > 0; off >>= 1) bp += __shfl_xor(bp, off);
  float bgate = 1.0f / (1.0f + __expf(-bp));
  float r0 = bgate * xrv.x + (1.0f - bgate) * o0;
  float r1 = bgate * xrv.y + (1.0f - bgate) * o1;

  float2 xv = *(const float2*)&x[(size_t)n * 128 + c0];
  float ge0 = 0.5f * r0 * (1.0f + erff(r0 * 0.70710678118654752f)) + xv.x;
  float ge1 = 0.5f * r1 * (1.0f + erff(r1 * 0.70710678118654752f)) + xv.y;

  float s1 = ge0 + ge1;
  float s2 = ge0 * ge0 + ge1 * ge1;
#pragma unroll
  for (int off = 32; off > 0; off >>= 1) {
    s1 += __shfl_xor(s1, off);
    s2 += __shfl_xor(s2, off);
  }
  float mean = s1 * (1.0f / 128.0f);
  float var = s2 * (1.0f / 128.0f) - mean * mean;
  float rstd = rsqrtf(var + 1e-5f);
  float2 ov;
  ov.x = (ge0 - mean) * rstd * gamma[c0] + beta_ln[c0];
  ov.y = (ge1 - mean) * rstd * gamma[c1] + beta_ln[c1];
  *(float2*)&out[(size_t)n * 128 + c0] = ov;
}

// ---------------- launch ----------------
extern "C" void kernel_launch(void* const* d_in, const int* in_sizes, int n_in,
                              void* d_out, int out_size, void* d_ws, size_t ws_size,
                              hipStream_t stream) {
  const float* x   = (const float*)d_in[0];
  const int*   ei  = (const int*)d_in[1];
  const float* ea  = (const float*)d_in[2];
  const float* Wq  = (const float*)d_in[3];
  const float* bq  = (const float*)d_in[4];
  const float* Wk  = (const float*)d_in[5];
  const float* bk  = (const float*)d_in[6];
  const float* Wv  = (const float*)d_in[7];
  const float* bv  = (const float*)d_in[8];
  const float* We  = (const float*)d_in[9];
  const float* Wsk = (const float*)d_in[10];
  const float* bsk = (const float*)d_in[11];
  const float* Wb  = (const float*)d_in[12];
  const float* gamma = (const float*)d_in[13];
  const float* beta  = (const float*)d_in[14];
  float* out = (float*)d_out;

  char* cur = (char*)d_ws;
  auto alloc = [&](size_t bytes) {
    void* p = (void*)cur;
    cur += (bytes + 255) & ~(size_t)255;
    return p;
  };
  ushort_t*      qbuf    = (ushort_t*)alloc((size_t)NN * 128 * 2);
  ushort_t*      kbuf    = (ushort_t*)alloc((size_t)NN * 128 * 2);
  ushort_t*      vbuf    = (ushort_t*)alloc((size_t)NN * 128 * 2);
  ushort_t*      xrbuf   = (ushort_t*)alloc((size_t)NN * 128 * 2);
  unsigned char* eaWperm = (unsigned char*)alloc((size_t)EE * 128); // fp8 eW, CSR order
  int*           srcs    = (int*)alloc((size_t)EE * 4);
  int*           rank    = (int*)alloc((size_t)EE * 4);
  float*         wcomb   = (float*)alloc(256 * 4);
  float*         bcat    = (float*)alloc(512 * 4);
  ushort_t*      Wbt     = (ushort_t*)alloc((size_t)512 * 128 * 2);
  ushort_t*      WebT    = (ushort_t*)alloc((size_t)128 * 64 * 2);
  int*           counts  = (int*)alloc((size_t)NN * 4);
  int*           offsets = (int*)alloc((size_t)(NN + 4) * 4);

  hipMemsetAsync(counts, 0, NN * sizeof(int), stream);
  k_prepB<<<289 + 3125, 256, 0, stream>>>(Wq, Wk, Wv, Wsk, bq, bk, bv, bsk,
                                          Wbt, bcat, We, WebT, Wb, wcomb,
                                          ei, counts, rank);
  k_mmscan<<<dim3(392, 4), 256, 0, stream>>>(x, Wbt, bcat, qbuf, kbuf, vbuf,
                                             xrbuf, counts, offsets);
  k_fillw<<<6250, 256, 0, stream>>>(ei, offsets, rank, ea, WebT, srcs, eaWperm);
  k_attn<<<12500, 256, 0, stream>>>(qbuf, xrbuf, kbuf, vbuf, eaWperm, offsets,
                                    srcs, x, wcomb, gamma, beta, out);
}